// Round 7
// baseline (4270.674 us; speedup 1.0000x reference)
//
#include <hip/hip_runtime.h>
#include <hip/hip_bf16.h>
#include <cstdint>

#define B_ 256
#define D_ 128
#define T_ 512
#define H_ 256
#define C_ 10
#define S32 0xFFFFFFFFu

using f32x4 = __attribute__((ext_vector_type(4))) float;
using s16x8 = __attribute__((ext_vector_type(8))) short;
using u32x4 = __attribute__((ext_vector_type(4))) unsigned int;

__device__ __forceinline__ unsigned short f2bf(float f) {
    union { float f; uint32_t u; } a; a.f = f;
    uint32_t u = a.u;
    uint32_t r = (u + 0x7fffu + ((u >> 16) & 1u)) >> 16;   // RNE
    return (unsigned short)r;
}

__device__ __forceinline__ float sigm(float v) { return 1.0f / (1.0f + __expf(-v)); }

// LDS-only barrier: does NOT drain vmcnt -> in-flight global loads/stores
// keep flying across it.
__device__ __forceinline__ void lds_barrier() {
    asm volatile("s_waitcnt lgkmcnt(0)" ::: "memory");
    __builtin_amdgcn_sched_barrier(0);
    __builtin_amdgcn_s_barrier();
    __builtin_amdgcn_sched_barrier(0);
}

// ---------------------------------------------------------------------------
// Kernel 1: transpose x [B][D][T] f32  ->  xt [T][B][D] bf16
// ---------------------------------------------------------------------------
__global__ void xt_kernel(const float* __restrict__ x, unsigned short* __restrict__ xt) {
    __shared__ unsigned short tile[128][66];
    const int b  = blockIdx.x >> 3;
    const int t0 = (blockIdx.x & 7) << 6;
    const int tid = threadIdx.x;
    const int j  = tid & 63;
    const int dq = tid >> 6;

#pragma unroll
    for (int it = 0; it < 32; ++it) {
        int d = it * 4 + dq;
        tile[d][j] = f2bf(x[(size_t)(b * D_ + d) * T_ + t0 + j]);
    }
    __syncthreads();

    uint32_t* xt32 = (uint32_t*)xt;
#pragma unroll
    for (int it = 0; it < 16; ++it) {
        int tl = it * 4 + dq;
        int dp = j;
        uint32_t lo = tile[2 * dp][tl];
        uint32_t hi = tile[2 * dp + 1][tl];
        xt32[(size_t)((t0 + tl) * B_ + b) * (D_ / 2) + dp] = lo | (hi << 16);
    }
}

// ---------------------------------------------------------------------------
// Kernel 2: persistent LSTM recurrence — clique-of-TWO (minimum possible
// inter-block communication for a unit-split recurrence).
// 32 blocks = 16 batch-chunks (bc) x 2 unit-halves (half); pair = (bc, 1-half)
// = blockIdx +/- 16 -> same XCD under round-robin dispatch.
// Block = 512 threads / 8 waves; wave owns 16 units x ALL 4 gates, all its
// weights (x:4 + h-own:4 + h-peer:4 K-slices x 4 gates = 192 VGPRs) in regs.
// Per step: own 128 h-units via XOR-swizzled LDS double buffer (one lgkm-only
// barrier, zero MALL); peer 128 h-units via ONE 4KB sentinel-validated slot
// loaded directly into MFMA A-fragments (sc1). Producers-per-consumer = 1.
// x A-fragments issued mid-step, hidden under the own-half MFMAs.
// ---------------------------------------------------------------------------
#define ISSUE_PV(p_)                                                                         \
    do {                                                                                     \
        asm volatile("global_load_dwordx4 %0, %1, off sc1"            : "=v"(pv0) : "v"(p_)); \
        asm volatile("global_load_dwordx4 %0, %1, off offset:64 sc1"  : "=v"(pv1) : "v"(p_)); \
        asm volatile("global_load_dwordx4 %0, %1, off offset:128 sc1" : "=v"(pv2) : "v"(p_)); \
        asm volatile("global_load_dwordx4 %0, %1, off offset:192 sc1" : "=v"(pv3) : "v"(p_)); \
    } while (0)

#define ISSUE_XV(p_)                                                                         \
    do {                                                                                     \
        asm volatile("global_load_dwordx4 %0, %1, off"            : "=v"(xv0) : "v"(p_));     \
        asm volatile("global_load_dwordx4 %0, %1, off offset:64"  : "=v"(xv1) : "v"(p_));     \
        asm volatile("global_load_dwordx4 %0, %1, off offset:128" : "=v"(xv2) : "v"(p_));     \
        asm volatile("global_load_dwordx4 %0, %1, off offset:192" : "=v"(xv3) : "v"(p_));     \
    } while (0)

__global__ void __launch_bounds__(512, 2) lstm_kernel(
    const float* __restrict__ Wgx, const float* __restrict__ Wix,
    const float* __restrict__ Wfx, const float* __restrict__ Wox,
    const float* __restrict__ Wgh, const float* __restrict__ Wih,
    const float* __restrict__ Wfh, const float* __restrict__ Woh,
    const float* __restrict__ bg,  const float* __restrict__ bi,
    const float* __restrict__ bf2, const float* __restrict__ bo,
    const unsigned short* __restrict__ xt,
    unsigned short* __restrict__ hbuf,
    float* __restrict__ hfin)
{
    // [buf][16 rows][128 units bf16] = 2 x 4 KB, XOR-swizzled byte layout
    __shared__ __align__(16) unsigned char h_s[2][4096];

    const int tid  = threadIdx.x;
    const int bc   = blockIdx.x & 15;          // batch chunk (16 rows)
    const int half = blockIdx.x >> 4;          // unit half (128 units)
    const int wv   = tid >> 6;                 // wave 0..7
    const int lane = tid & 63;
    const int mrow = lane & 15;
    const int quad = lane >> 4;
    const int u    = half * 128 + wv * 16 + mrow;   // this lane's output unit
    const int swz  = (mrow & 7) << 4;               // read-side row swizzle

    const float* WxA[4] = {Wgx, Wix, Wfx, Wox};
    const float* WhA[4] = {Wgh, Wih, Wfh, Woh};

    // ---- one-time: 48 B-fragments into registers ------------------------
    // wx[g][i]  : x K-slice i            (k = i*32+quad*8+j)
    // who[g][i] : own-half h K-slice     (k = half*128 + i*32+quad*8+j)
    // whp[g][i] : peer-half h K-slice    (k = (1-half)*128 + i*32+quad*8+j)
    s16x8 wx[4][4], who[4][4], whp[4][4];
#pragma unroll
    for (int g = 0; g < 4; ++g) {
#pragma unroll
        for (int i = 0; i < 4; ++i) {
            const float* s1 = WxA[g] + (size_t)(i * 32 + quad * 8) * H_ + u;
            const float* s2 = WhA[g] + (size_t)((half * 4 + i) * 32 + quad * 8) * H_ + u;
            const float* s3 = WhA[g] + (size_t)(((1 - half) * 4 + i) * 32 + quad * 8) * H_ + u;
            s16x8 a, b, c;
#pragma unroll
            for (int j = 0; j < 8; ++j) {
                a[j] = (short)f2bf(s1[(size_t)j * H_]);
                b[j] = (short)f2bf(s2[(size_t)j * H_]);
                c[j] = (short)f2bf(s3[(size_t)j * H_]);
            }
            wx[g][i] = a; who[g][i] = b; whp[g][i] = c;
        }
    }
    const float bs0 = bg[u], bs1 = bi[u], bs2 = bf2[u], bs3 = bo[u];

    float cst[4] = {0.f, 0.f, 0.f, 0.f};
    float hst[4] = {0.f, 0.f, 0.f, 0.f};

    u32x4 pv0, pv1, pv2, pv3;      // peer-half h A-fragments
    u32x4 xv0, xv1, xv2, xv3;      // x A-fragments

    const size_t arow = (size_t)(bc * 16 + mrow);
    const size_t SLOT = (size_t)B_ * H_;       // 65536 elems per time slot
    const int area_me   = bc * 2 + half;       // my 16x128 area within a slot
    const int area_peer = bc * 2 + (1 - half);

    const unsigned short* xp  = xt + arow * D_ + quad * 8;
    const unsigned short* pvp = hbuf + (size_t)area_peer * 2048 + mrow * 128 + quad * 8;
    unsigned short*       stp = hbuf + (size_t)area_me * 2048 + wv * 16 + (mrow & ~3);

    f32x4 acc[4];
    uint64_t stv[4];

    // =====================  prologue: t = 0  =============================
    {
        u32x4 x0 = *(const u32x4*)(xp);
        u32x4 x1 = *(const u32x4*)(xp + 32);
        u32x4 x2 = *(const u32x4*)(xp + 64);
        u32x4 x3 = *(const u32x4*)(xp + 96);
        acc[0] = (f32x4){bs0, bs0, bs0, bs0};
        acc[1] = (f32x4){bs1, bs1, bs1, bs1};
        acc[2] = (f32x4){bs2, bs2, bs2, bs2};
        acc[3] = (f32x4){bs3, bs3, bs3, bs3};
#pragma unroll
        for (int g = 0; g < 4; ++g) {
            acc[g] = __builtin_amdgcn_mfma_f32_16x16x32_bf16(__builtin_bit_cast(s16x8, x0), wx[g][0], acc[g], 0, 0, 0);
            acc[g] = __builtin_amdgcn_mfma_f32_16x16x32_bf16(__builtin_bit_cast(s16x8, x1), wx[g][1], acc[g], 0, 0, 0);
            acc[g] = __builtin_amdgcn_mfma_f32_16x16x32_bf16(__builtin_bit_cast(s16x8, x2), wx[g][2], acc[g], 0, 0, 0);
            acc[g] = __builtin_amdgcn_mfma_f32_16x16x32_bf16(__builtin_bit_cast(s16x8, x3), wx[g][3], acc[g], 0, 0, 0);
        }
    }
#pragma unroll
    for (int r = 0; r < 4; ++r) {
        float gg = 2.0f * sigm(2.0f * acc[0][r]) - 1.0f;   // tanh
        float ii = sigm(acc[1][r]), ff = sigm(acc[2][r]), oo = sigm(acc[3][r]);
        cst[r] = gg * ii + cst[r] * ff;
        hst[r] = (2.0f * sigm(2.0f * cst[r]) - 1.0f) * oo;
    }
#pragma unroll
    for (int r = 0; r < 4; ++r) {
        uint32_t hb = f2bf(hst[r]);
        uint32_t p2 = hb | ((uint32_t)__shfl_down((int)hb, 1, 64) << 16);
        uint32_t q2 = (uint32_t)__shfl_down((int)p2, 2, 64);
        stv[r] = ((uint64_t)q2 << 32) | (uint64_t)p2;
    }
#pragma unroll
    for (int r = 0; r < 4; ++r) {
        const int row = quad * 4 + r;
        if ((mrow & 3) == 0) {
            // own half -> LDS buf 0 (write-side swizzle keyed on dest row)
            *(uint64_t*)&h_s[0][(row * 256 + wv * 32 + (mrow & ~3) * 2) ^ ((row & 7) << 4)] = stv[r];
            // peer-visible copy -> slot 0
            __hip_atomic_store((uint64_t*)(stp + (size_t)row * 128), stv[r],
                               __ATOMIC_RELAXED, __HIP_MEMORY_SCOPE_AGENT);
        }
    }
    __builtin_amdgcn_sched_barrier(0);
    ISSUE_PV(pvp);                     // peer slot 0 (race-tolerant, sentinel-checked)
    __builtin_amdgcn_sched_barrier(0);

    // =====================  steady loop t = 1..511  ======================
    for (int t = 1; t < T_; ++t) {
        lds_barrier();                 // all waves' h_s writes of t-1 visible
        asm volatile("s_waitcnt vmcnt(0)" ::: "memory");   // pv(t-1) + store acks
        __builtin_amdgcn_sched_barrier(0);

        // sentinel poll on the single peer payload; retry re-issues + drains
        for (;;) {
            uint32_t m = 0;
#pragma unroll
            for (int i = 0; i < 4; ++i) {
                m = m > pv0[i] ? m : pv0[i];
                m = m > pv1[i] ? m : pv1[i];
                m = m > pv2[i] ? m : pv2[i];
                m = m > pv3[i] ? m : pv3[i];
            }
            if (__all(m != S32)) break;
            __builtin_amdgcn_s_sleep(1);
            ISSUE_PV(pvp);
            asm volatile("s_waitcnt vmcnt(0)" ::: "memory");
            __builtin_amdgcn_sched_barrier(0);
        }

        acc[0] = (f32x4){bs0, bs0, bs0, bs0};
        acc[1] = (f32x4){bs1, bs1, bs1, bs1};
        acc[2] = (f32x4){bs2, bs2, bs2, bs2};
        acc[3] = (f32x4){bs3, bs3, bs3, bs3};

        // peer-half h MFMAs straight from the payload fragments
#pragma unroll
        for (int g = 0; g < 4; ++g) {
            acc[g] = __builtin_amdgcn_mfma_f32_16x16x32_bf16(__builtin_bit_cast(s16x8, pv0), whp[g][0], acc[g], 0, 0, 0);
            acc[g] = __builtin_amdgcn_mfma_f32_16x16x32_bf16(__builtin_bit_cast(s16x8, pv1), whp[g][1], acc[g], 0, 0, 0);
            acc[g] = __builtin_amdgcn_mfma_f32_16x16x32_bf16(__builtin_bit_cast(s16x8, pv2), whp[g][2], acc[g], 0, 0, 0);
            acc[g] = __builtin_amdgcn_mfma_f32_16x16x32_bf16(__builtin_bit_cast(s16x8, pv3), whp[g][3], acc[g], 0, 0, 0);
        }

        // issue x(t) now; its latency hides under the own-half MFMAs
        xp += (size_t)B_ * D_;
        ISSUE_XV(xp);
        __builtin_amdgcn_sched_barrier(0);

        // own-half h MFMAs from swizzled LDS
        {
            const int pr = (t - 1) & 1;
            s16x8 ha0 = *(const s16x8*)&h_s[pr][(mrow * 256 +   0 + quad * 16) ^ swz];
            s16x8 ha1 = *(const s16x8*)&h_s[pr][(mrow * 256 +  64 + quad * 16) ^ swz];
            s16x8 ha2 = *(const s16x8*)&h_s[pr][(mrow * 256 + 128 + quad * 16) ^ swz];
            s16x8 ha3 = *(const s16x8*)&h_s[pr][(mrow * 256 + 192 + quad * 16) ^ swz];
#pragma unroll
            for (int g = 0; g < 4; ++g) {
                acc[g] = __builtin_amdgcn_mfma_f32_16x16x32_bf16(ha0, who[g][0], acc[g], 0, 0, 0);
                acc[g] = __builtin_amdgcn_mfma_f32_16x16x32_bf16(ha1, who[g][1], acc[g], 0, 0, 0);
                acc[g] = __builtin_amdgcn_mfma_f32_16x16x32_bf16(ha2, who[g][2], acc[g], 0, 0, 0);
                acc[g] = __builtin_amdgcn_mfma_f32_16x16x32_bf16(ha3, who[g][3], acc[g], 0, 0, 0);
            }
        }

        // x MFMAs
        asm volatile("s_waitcnt vmcnt(0)" ::: "memory");   // xv ready
        __builtin_amdgcn_sched_barrier(0);
#pragma unroll
        for (int g = 0; g < 4; ++g) {
            acc[g] = __builtin_amdgcn_mfma_f32_16x16x32_bf16(__builtin_bit_cast(s16x8, xv0), wx[g][0], acc[g], 0, 0, 0);
            acc[g] = __builtin_amdgcn_mfma_f32_16x16x32_bf16(__builtin_bit_cast(s16x8, xv1), wx[g][1], acc[g], 0, 0, 0);
            acc[g] = __builtin_amdgcn_mfma_f32_16x16x32_bf16(__builtin_bit_cast(s16x8, xv2), wx[g][2], acc[g], 0, 0, 0);
            acc[g] = __builtin_amdgcn_mfma_f32_16x16x32_bf16(__builtin_bit_cast(s16x8, xv3), wx[g][3], acc[g], 0, 0, 0);
        }

        // activation fully in-register (rows quad*4+r, unit u)
#pragma unroll
        for (int r = 0; r < 4; ++r) {
            float gg = 2.0f * sigm(2.0f * acc[0][r]) - 1.0f;
            float ii = sigm(acc[1][r]), ff = sigm(acc[2][r]), oo = sigm(acc[3][r]);
            cst[r] = gg * ii + cst[r] * ff;
            hst[r] = (2.0f * sigm(2.0f * cst[r]) - 1.0f) * oo;
        }

        // pack unit quads
#pragma unroll
        for (int r = 0; r < 4; ++r) {
            uint32_t hb = f2bf(hst[r]);
            uint32_t p2 = hb | ((uint32_t)__shfl_down((int)hb, 1, 64) << 16);
            uint32_t q2 = (uint32_t)__shfl_down((int)p2, 2, 64);
            stv[r] = ((uint64_t)q2 << 32) | (uint64_t)p2;
        }

        // own half -> LDS (other buffer); peer copy -> slot t
        const int cw = t & 1;
        stp += SLOT;
#pragma unroll
        for (int r = 0; r < 4; ++r) {
            const int row = quad * 4 + r;
            if ((mrow & 3) == 0) {
                *(uint64_t*)&h_s[cw][(row * 256 + wv * 32 + (mrow & ~3) * 2) ^ ((row & 7) << 4)] = stv[r];
                __hip_atomic_store((uint64_t*)(stp + (size_t)row * 128), stv[r],
                                   __ATOMIC_RELAXED, __HIP_MEMORY_SCOPE_AGENT);
            }
        }
        __builtin_amdgcn_sched_barrier(0);

        // early-issue next step's peer payload (slot t)
        pvp += SLOT;
        ISSUE_PV(pvp);
        __builtin_amdgcn_sched_barrier(0);
    }

#pragma unroll
    for (int r = 0; r < 4; ++r)
        hfin[(size_t)(bc * 16 + quad * 4 + r) * H_ + u] = hst[r];
}

// ---------------------------------------------------------------------------
// Kernel 3: out = h_final @ W_ph + b_p
// ---------------------------------------------------------------------------
__global__ void proj_kernel(const float* __restrict__ hfin, const float* __restrict__ Wph,
                            const float* __restrict__ bp, float* __restrict__ out) {
    int gid = blockIdx.x * 256 + threadIdx.x;
    if (gid >= B_ * C_) return;
    int b = gid / C_, cc = gid % C_;
    float acc = bp[cc];
#pragma unroll 8
    for (int u = 0; u < H_; ++u)
        acc += hfin[(size_t)b * H_ + u] * Wph[(size_t)u * C_ + cc];
    out[gid] = acc;
}

// ---------------------------------------------------------------------------
extern "C" void kernel_launch(void* const* d_in, const int* in_sizes, int n_in,
                              void* d_out, int out_size, void* d_ws, size_t ws_size,
                              hipStream_t stream) {
    const float* x   = (const float*)d_in[0];
    const float* Wgx = (const float*)d_in[1];
    const float* Wix = (const float*)d_in[2];
    const float* Wfx = (const float*)d_in[3];
    const float* Wox = (const float*)d_in[4];
    const float* Wgh = (const float*)d_in[5];
    const float* Wih = (const float*)d_in[6];
    const float* Wfh = (const float*)d_in[7];
    const float* Woh = (const float*)d_in[8];
    const float* bg  = (const float*)d_in[9];
    const float* bi  = (const float*)d_in[10];
    const float* bf2 = (const float*)d_in[11];
    const float* bo  = (const float*)d_in[12];
    const float* Wph = (const float*)d_in[13];
    const float* bp  = (const float*)d_in[14];

    const size_t hbuf_bytes = (size_t)T_ * B_ * H_ * 2;   // 64 MB bf16, [T][bc][half][16][128]

    char* ws = (char*)d_ws;
    unsigned short* hbuf = (unsigned short*)ws;
    float*          hfin = (float*)(ws + hbuf_bytes);
    unsigned short* xt   = (unsigned short*)(ws + hbuf_bytes + (size_t)B_ * H_ * sizeof(float));

    // sentinel-fill the h exchange buffer (bf16 NaN pattern 0xFFFF)
    hipMemsetAsync(hbuf, 0xFF, hbuf_bytes, stream);

    xt_kernel<<<B_ * (T_ / 64), 256, 0, stream>>>(x, xt);

    lstm_kernel<<<32, 512, 0, stream>>>(Wgx, Wix, Wfx, Wox, Wgh, Wih, Wfh, Woh,
                                        bg, bi, bf2, bo, xt, hbuf, hfin);

    proj_kernel<<<(B_ * C_ + 255) / 256, 256, 0, stream>>>(hfin, Wph, bp, (float*)d_out);
}

// Round 8
// 2444.662 us; speedup vs baseline: 1.7469x; 1.7469x over previous
//
#include <hip/hip_runtime.h>
#include <hip/hip_bf16.h>
#include <cstdint>

#define B_ 256
#define D_ 128
#define T_ 512
#define H_ 256
#define C_ 10
#define S32 0xFFFFFFFFu

using f32x4 = __attribute__((ext_vector_type(4))) float;
using s16x8 = __attribute__((ext_vector_type(8))) short;
using u32x4 = __attribute__((ext_vector_type(4))) unsigned int;

__device__ __forceinline__ unsigned short f2bf(float f) {
    union { float f; uint32_t u; } a; a.f = f;
    uint32_t u = a.u;
    uint32_t r = (u + 0x7fffu + ((u >> 16) & 1u)) >> 16;   // RNE
    return (unsigned short)r;
}

__device__ __forceinline__ float sigm(float v) { return 1.0f / (1.0f + __expf(-v)); }

// LDS-only barrier: does NOT drain vmcnt -> in-flight global loads/stores
// keep flying across it.
__device__ __forceinline__ void lds_barrier() {
    asm volatile("s_waitcnt lgkmcnt(0)" ::: "memory");
    __builtin_amdgcn_sched_barrier(0);
    __builtin_amdgcn_s_barrier();
    __builtin_amdgcn_sched_barrier(0);
}

// ---------------------------------------------------------------------------
// Kernel 1: transpose x [B][D][T] f32  ->  xt [T][B][D] bf16
// ---------------------------------------------------------------------------
__global__ void xt_kernel(const float* __restrict__ x, unsigned short* __restrict__ xt) {
    __shared__ unsigned short tile[128][66];
    const int b  = blockIdx.x >> 3;
    const int t0 = (blockIdx.x & 7) << 6;
    const int tid = threadIdx.x;
    const int j  = tid & 63;
    const int dq = tid >> 6;

#pragma unroll
    for (int it = 0; it < 32; ++it) {
        int d = it * 4 + dq;
        tile[d][j] = f2bf(x[(size_t)(b * D_ + d) * T_ + t0 + j]);
    }
    __syncthreads();

    uint32_t* xt32 = (uint32_t*)xt;
#pragma unroll
    for (int it = 0; it < 16; ++it) {
        int tl = it * 4 + dq;
        int dp = j;
        uint32_t lo = tile[2 * dp][tl];
        uint32_t hi = tile[2 * dp + 1][tl];
        xt32[(size_t)((t0 + tl) * B_ + b) * (D_ / 2) + dp] = lo | (hi << 16);
    }
}

// ---------------------------------------------------------------------------
// Kernel 2: persistent LSTM recurrence — clique-of-TWO, register-budget fixed.
// 32 blocks = 16 batch-chunks (bc) x 2 unit-halves; pair = blockIdx +/- 16
// (same XCD under round-robin dispatch). 512 threads / 8 waves; wave owns
// 16 units x ALL 4 gates.
// Register budget (the R7 killer): launch_bounds(512,1) -> 256 VGPR cap;
// h-weights (own+peer, 128 VGPRs) in registers; x-weights in per-wave LDS
// regions (128 KB), one conflict-free ds_read_b128 per fragment per step
// (opaque offset defeats re-hoisting). Design sits ~212 VGPRs.
// Exchange: own 128 h-units via XOR-swizzled LDS double buffer (one
// lgkm-only barrier/step); peer 128 units via ONE 4 KB sentinel slot
// (0xFF = bf16 NaN) loaded directly into MFMA A-fragments (sc1).
// Single vmcnt(0) per step retires {stores(t-1), pv(t-1), xv(t)}.
// ---------------------------------------------------------------------------
#define ISSUE_PV(p_)                                                                          \
    do {                                                                                      \
        asm volatile("global_load_dwordx4 %0, %1, off sc1"            : "=v"(pv0) : "v"(p_)); \
        asm volatile("global_load_dwordx4 %0, %1, off offset:64 sc1"  : "=v"(pv1) : "v"(p_)); \
        asm volatile("global_load_dwordx4 %0, %1, off offset:128 sc1" : "=v"(pv2) : "v"(p_)); \
        asm volatile("global_load_dwordx4 %0, %1, off offset:192 sc1" : "=v"(pv3) : "v"(p_)); \
    } while (0)

#define ISSUE_XV(p_)                                                                          \
    do {                                                                                      \
        asm volatile("global_load_dwordx4 %0, %1, off"            : "=v"(xv0) : "v"(p_));     \
        asm volatile("global_load_dwordx4 %0, %1, off offset:64"  : "=v"(xv1) : "v"(p_));     \
        asm volatile("global_load_dwordx4 %0, %1, off offset:128" : "=v"(xv2) : "v"(p_));     \
        asm volatile("global_load_dwordx4 %0, %1, off offset:192" : "=v"(xv3) : "v"(p_));     \
    } while (0)

__global__ void __launch_bounds__(512, 1) lstm_kernel(
    const float* __restrict__ Wgx, const float* __restrict__ Wix,
    const float* __restrict__ Wfx, const float* __restrict__ Wox,
    const float* __restrict__ Wgh, const float* __restrict__ Wih,
    const float* __restrict__ Wfh, const float* __restrict__ Woh,
    const float* __restrict__ bg,  const float* __restrict__ bi,
    const float* __restrict__ bf2, const float* __restrict__ bo,
    const unsigned short* __restrict__ xt,
    unsigned short* __restrict__ hbuf,
    float* __restrict__ hfin)
{
    // per-wave x-weight regions: 8 waves x 16 frags x 1 KB
    __shared__ __align__(16) unsigned char wx_lds[131072];
    // [buf][16 rows][128 units bf16] = 2 x 4 KB, XOR-swizzled byte layout
    __shared__ __align__(16) unsigned char h_s[2][4096];

    const int tid  = threadIdx.x;
    const int bc   = blockIdx.x & 15;          // batch chunk (16 rows)
    const int half = blockIdx.x >> 4;          // unit half (128 units)
    const int wv   = tid >> 6;                 // wave 0..7
    const int lane = tid & 63;
    const int mrow = lane & 15;
    const int quad = lane >> 4;
    const int u    = half * 128 + wv * 16 + mrow;   // this lane's output unit
    const int swz  = (mrow & 7) << 4;               // read-side row swizzle

    const float* WxA[4] = {Wgx, Wix, Wfx, Wox};
    const float* WhA[4] = {Wgh, Wih, Wfh, Woh};

    // ---- one-time staging ------------------------------------------------
    // x-weights -> per-wave LDS (frag f=g*4+i at region (wv*16+f)*1024,
    // lane's 16B at +lane*16 -> stride-16 conflict-free ds_read_b128)
#pragma unroll
    for (int g = 0; g < 4; ++g) {
#pragma unroll
        for (int i = 0; i < 4; ++i) {
            const float* s1 = WxA[g] + (size_t)(i * 32 + quad * 8) * H_ + u;
            s16x8 a;
#pragma unroll
            for (int j = 0; j < 8; ++j) a[j] = (short)f2bf(s1[(size_t)j * H_]);
            *(s16x8*)&wx_lds[(unsigned)((wv * 16 + g * 4 + i) << 10) + (unsigned)lane * 16] = a;
        }
    }
    // h-weights (own + peer halves) -> registers (128 VGPRs)
    s16x8 who[4][4], whp[4][4];
#pragma unroll
    for (int g = 0; g < 4; ++g) {
#pragma unroll
        for (int i = 0; i < 4; ++i) {
            const float* s2 = WhA[g] + (size_t)((half * 4 + i) * 32 + quad * 8) * H_ + u;
            const float* s3 = WhA[g] + (size_t)(((1 - half) * 4 + i) * 32 + quad * 8) * H_ + u;
            s16x8 b, c;
#pragma unroll
            for (int j = 0; j < 8; ++j) {
                b[j] = (short)f2bf(s2[(size_t)j * H_]);
                c[j] = (short)f2bf(s3[(size_t)j * H_]);
            }
            who[g][i] = b; whp[g][i] = c;
        }
    }
    const float bs0 = bg[u], bs1 = bi[u], bs2 = bf2[u], bs3 = bo[u];
    __syncthreads();   // wx_lds ready

    float cst[4] = {0.f, 0.f, 0.f, 0.f};
    float hst[4] = {0.f, 0.f, 0.f, 0.f};

    u32x4 pv0, pv1, pv2, pv3;      // peer-half h A-fragments
    u32x4 xv0, xv1, xv2, xv3;      // x A-fragments

    const size_t arow = (size_t)(bc * 16 + mrow);
    const size_t SLOT = (size_t)B_ * H_;       // 65536 elems per time slot
    const int area_me   = bc * 2 + half;       // my 16x128 area within a slot
    const int area_peer = bc * 2 + (1 - half);

    const unsigned short* xp  = xt + arow * D_ + quad * 8;
    const unsigned short* pvp = hbuf + (size_t)area_peer * 2048 + mrow * 128 + quad * 8;
    unsigned short*       stp = hbuf + (size_t)area_me * 2048 + wv * 16 + (mrow & ~3);

    f32x4 acc[4];
    uint64_t stv[4];

    // =====================  prologue: t = 0  =============================
    ISSUE_XV(xp);
    asm volatile("s_waitcnt vmcnt(0)" ::: "memory");
    __builtin_amdgcn_sched_barrier(0);

    acc[0] = (f32x4){bs0, bs0, bs0, bs0};
    acc[1] = (f32x4){bs1, bs1, bs1, bs1};
    acc[2] = (f32x4){bs2, bs2, bs2, bs2};
    acc[3] = (f32x4){bs3, bs3, bs3, bs3};
    {
        unsigned wxo = (unsigned)(wv << 14) + (unsigned)lane * 16;
        asm volatile("" : "+v"(wxo));
#pragma unroll
        for (int g = 0; g < 4; ++g) {
            s16x8 f0 = *(const s16x8*)&wx_lds[wxo + ((g * 4 + 0) << 10)];
            s16x8 f1 = *(const s16x8*)&wx_lds[wxo + ((g * 4 + 1) << 10)];
            s16x8 f2 = *(const s16x8*)&wx_lds[wxo + ((g * 4 + 2) << 10)];
            s16x8 f3 = *(const s16x8*)&wx_lds[wxo + ((g * 4 + 3) << 10)];
            acc[g] = __builtin_amdgcn_mfma_f32_16x16x32_bf16(__builtin_bit_cast(s16x8, xv0), f0, acc[g], 0, 0, 0);
            acc[g] = __builtin_amdgcn_mfma_f32_16x16x32_bf16(__builtin_bit_cast(s16x8, xv1), f1, acc[g], 0, 0, 0);
            acc[g] = __builtin_amdgcn_mfma_f32_16x16x32_bf16(__builtin_bit_cast(s16x8, xv2), f2, acc[g], 0, 0, 0);
            acc[g] = __builtin_amdgcn_mfma_f32_16x16x32_bf16(__builtin_bit_cast(s16x8, xv3), f3, acc[g], 0, 0, 0);
        }
    }
#pragma unroll
    for (int r = 0; r < 4; ++r) {
        float gg = 2.0f * sigm(2.0f * acc[0][r]) - 1.0f;   // tanh
        float ii = sigm(acc[1][r]), ff = sigm(acc[2][r]), oo = sigm(acc[3][r]);
        cst[r] = gg * ii + cst[r] * ff;
        hst[r] = (2.0f * sigm(2.0f * cst[r]) - 1.0f) * oo;
    }
#pragma unroll
    for (int r = 0; r < 4; ++r) {
        uint32_t hb = f2bf(hst[r]);
        uint32_t p2 = hb | ((uint32_t)__shfl_down((int)hb, 1, 64) << 16);
        uint32_t q2 = (uint32_t)__shfl_down((int)p2, 2, 64);
        stv[r] = ((uint64_t)q2 << 32) | (uint64_t)p2;
    }
#pragma unroll
    for (int r = 0; r < 4; ++r) {
        const int row = quad * 4 + r;
        if ((mrow & 3) == 0) {
            *(uint64_t*)&h_s[0][(row * 256 + wv * 32 + (mrow & ~3) * 2) ^ ((row & 7) << 4)] = stv[r];
            __hip_atomic_store((uint64_t*)(stp + (size_t)row * 128), stv[r],
                               __ATOMIC_RELAXED, __HIP_MEMORY_SCOPE_AGENT);
        }
    }
    __builtin_amdgcn_sched_barrier(0);
    ISSUE_PV(pvp);                                   // peer slot 0
    ISSUE_XV(xp + (size_t)B_ * D_);                  // x(1)
    __builtin_amdgcn_sched_barrier(0);

    // =====================  steady loop t = 1..511  ======================
    for (int t = 1; t < T_; ++t) {
        lds_barrier();                               // h_s(t-1) from all waves
        asm volatile("s_waitcnt vmcnt(0)" ::: "memory");  // st(t-1)+pv(t-1)+xv(t)
        __builtin_amdgcn_sched_barrier(0);

        // sentinel poll on the single peer payload; retry re-issues + drains
        for (;;) {
            uint32_t m = 0;
#pragma unroll
            for (int i = 0; i < 4; ++i) {
                m = m > pv0[i] ? m : pv0[i];
                m = m > pv1[i] ? m : pv1[i];
                m = m > pv2[i] ? m : pv2[i];
                m = m > pv3[i] ? m : pv3[i];
            }
            if (__all(m != S32)) break;
            __builtin_amdgcn_s_sleep(1);
            ISSUE_PV(pvp);
            asm volatile("s_waitcnt vmcnt(0)" ::: "memory");
            __builtin_amdgcn_sched_barrier(0);
        }

        acc[0] = (f32x4){bs0, bs0, bs0, bs0};
        acc[1] = (f32x4){bs1, bs1, bs1, bs1};
        acc[2] = (f32x4){bs2, bs2, bs2, bs2};
        acc[3] = (f32x4){bs3, bs3, bs3, bs3};

        // peer-half h MFMAs straight from the payload fragments
#pragma unroll
        for (int g = 0; g < 4; ++g) {
            acc[g] = __builtin_amdgcn_mfma_f32_16x16x32_bf16(__builtin_bit_cast(s16x8, pv0), whp[g][0], acc[g], 0, 0, 0);
            acc[g] = __builtin_amdgcn_mfma_f32_16x16x32_bf16(__builtin_bit_cast(s16x8, pv1), whp[g][1], acc[g], 0, 0, 0);
            acc[g] = __builtin_amdgcn_mfma_f32_16x16x32_bf16(__builtin_bit_cast(s16x8, pv2), whp[g][2], acc[g], 0, 0, 0);
            acc[g] = __builtin_amdgcn_mfma_f32_16x16x32_bf16(__builtin_bit_cast(s16x8, pv3), whp[g][3], acc[g], 0, 0, 0);
        }

        // own-half h MFMAs from swizzled LDS
        {
            const int pr = (t - 1) & 1;
            s16x8 ha0 = *(const s16x8*)&h_s[pr][(mrow * 256 +   0 + quad * 16) ^ swz];
            s16x8 ha1 = *(const s16x8*)&h_s[pr][(mrow * 256 +  64 + quad * 16) ^ swz];
            s16x8 ha2 = *(const s16x8*)&h_s[pr][(mrow * 256 + 128 + quad * 16) ^ swz];
            s16x8 ha3 = *(const s16x8*)&h_s[pr][(mrow * 256 + 192 + quad * 16) ^ swz];
#pragma unroll
            for (int g = 0; g < 4; ++g) {
                acc[g] = __builtin_amdgcn_mfma_f32_16x16x32_bf16(ha0, who[g][0], acc[g], 0, 0, 0);
                acc[g] = __builtin_amdgcn_mfma_f32_16x16x32_bf16(ha1, who[g][1], acc[g], 0, 0, 0);
                acc[g] = __builtin_amdgcn_mfma_f32_16x16x32_bf16(ha2, who[g][2], acc[g], 0, 0, 0);
                acc[g] = __builtin_amdgcn_mfma_f32_16x16x32_bf16(ha3, who[g][3], acc[g], 0, 0, 0);
            }
        }

        // x MFMAs (xv loaded last step; Wx frags re-read from LDS each step)
        {
            unsigned wxo = (unsigned)(wv << 14) + (unsigned)lane * 16;
            asm volatile("" : "+v"(wxo));
#pragma unroll
            for (int g = 0; g < 4; ++g) {
                s16x8 f0 = *(const s16x8*)&wx_lds[wxo + ((g * 4 + 0) << 10)];
                s16x8 f1 = *(const s16x8*)&wx_lds[wxo + ((g * 4 + 1) << 10)];
                s16x8 f2 = *(const s16x8*)&wx_lds[wxo + ((g * 4 + 2) << 10)];
                s16x8 f3 = *(const s16x8*)&wx_lds[wxo + ((g * 4 + 3) << 10)];
                acc[g] = __builtin_amdgcn_mfma_f32_16x16x32_bf16(__builtin_bit_cast(s16x8, xv0), f0, acc[g], 0, 0, 0);
                acc[g] = __builtin_amdgcn_mfma_f32_16x16x32_bf16(__builtin_bit_cast(s16x8, xv1), f1, acc[g], 0, 0, 0);
                acc[g] = __builtin_amdgcn_mfma_f32_16x16x32_bf16(__builtin_bit_cast(s16x8, xv2), f2, acc[g], 0, 0, 0);
                acc[g] = __builtin_amdgcn_mfma_f32_16x16x32_bf16(__builtin_bit_cast(s16x8, xv3), f3, acc[g], 0, 0, 0);
            }
        }

        // activation fully in-register (rows quad*4+r, unit u)
#pragma unroll
        for (int r = 0; r < 4; ++r) {
            float gg = 2.0f * sigm(2.0f * acc[0][r]) - 1.0f;
            float ii = sigm(acc[1][r]), ff = sigm(acc[2][r]), oo = sigm(acc[3][r]);
            cst[r] = gg * ii + cst[r] * ff;
            hst[r] = (2.0f * sigm(2.0f * cst[r]) - 1.0f) * oo;
        }

        // pack unit quads
#pragma unroll
        for (int r = 0; r < 4; ++r) {
            uint32_t hb = f2bf(hst[r]);
            uint32_t p2 = hb | ((uint32_t)__shfl_down((int)hb, 1, 64) << 16);
            uint32_t q2 = (uint32_t)__shfl_down((int)p2, 2, 64);
            stv[r] = ((uint64_t)q2 << 32) | (uint64_t)p2;
        }

        // own half -> LDS (other buffer); peer copy -> slot t (stores first)
        const int cw = t & 1;
        stp += SLOT;
#pragma unroll
        for (int r = 0; r < 4; ++r) {
            const int row = quad * 4 + r;
            if ((mrow & 3) == 0) {
                *(uint64_t*)&h_s[cw][(row * 256 + wv * 32 + (mrow & ~3) * 2) ^ ((row & 7) << 4)] = stv[r];
                __hip_atomic_store((uint64_t*)(stp + (size_t)row * 128), stv[r],
                                   __ATOMIC_RELAXED, __HIP_MEMORY_SCOPE_AGENT);
            }
        }
        __builtin_amdgcn_sched_barrier(0);

        // early-issue next step's peer payload (slot t) + x(t+1, clamped)
        pvp += SLOT;
        ISSUE_PV(pvp);
        {
            size_t tn = (t + 1 < T_) ? (size_t)(t + 1) : (size_t)(T_ - 1);
            ISSUE_XV(xt + tn * B_ * D_ + arow * D_ + quad * 8);
        }
        __builtin_amdgcn_sched_barrier(0);
    }

#pragma unroll
    for (int r = 0; r < 4; ++r)
        hfin[(size_t)(bc * 16 + quad * 4 + r) * H_ + u] = hst[r];
}

// ---------------------------------------------------------------------------
// Kernel 3: out = h_final @ W_ph + b_p
// ---------------------------------------------------------------------------
__global__ void proj_kernel(const float* __restrict__ hfin, const float* __restrict__ Wph,
                            const float* __restrict__ bp, float* __restrict__ out) {
    int gid = blockIdx.x * 256 + threadIdx.x;
    if (gid >= B_ * C_) return;
    int b = gid / C_, cc = gid % C_;
    float acc = bp[cc];
#pragma unroll 8
    for (int u = 0; u < H_; ++u)
        acc += hfin[(size_t)b * H_ + u] * Wph[(size_t)u * C_ + cc];
    out[gid] = acc;
}

// ---------------------------------------------------------------------------
extern "C" void kernel_launch(void* const* d_in, const int* in_sizes, int n_in,
                              void* d_out, int out_size, void* d_ws, size_t ws_size,
                              hipStream_t stream) {
    const float* x   = (const float*)d_in[0];
    const float* Wgx = (const float*)d_in[1];
    const float* Wix = (const float*)d_in[2];
    const float* Wfx = (const float*)d_in[3];
    const float* Wox = (const float*)d_in[4];
    const float* Wgh = (const float*)d_in[5];
    const float* Wih = (const float*)d_in[6];
    const float* Wfh = (const float*)d_in[7];
    const float* Woh = (const float*)d_in[8];
    const float* bg  = (const float*)d_in[9];
    const float* bi  = (const float*)d_in[10];
    const float* bf2 = (const float*)d_in[11];
    const float* bo  = (const float*)d_in[12];
    const float* Wph = (const float*)d_in[13];
    const float* bp  = (const float*)d_in[14];

    const size_t hbuf_bytes = (size_t)T_ * B_ * H_ * 2;   // 64 MB bf16, [T][area32][16][128]

    char* ws = (char*)d_ws;
    unsigned short* hbuf = (unsigned short*)ws;
    float*          hfin = (float*)(ws + hbuf_bytes);
    unsigned short* xt   = (unsigned short*)(ws + hbuf_bytes + (size_t)B_ * H_ * sizeof(float));

    // sentinel-fill the h exchange buffer (bf16 NaN pattern 0xFFFF)
    hipMemsetAsync(hbuf, 0xFF, hbuf_bytes, stream);

    xt_kernel<<<B_ * (T_ / 64), 256, 0, stream>>>(x, xt);

    lstm_kernel<<<32, 512, 0, stream>>>(Wgx, Wix, Wfx, Wox, Wgh, Wih, Wfh, Woh,
                                        bg, bi, bf2, bo, xt, hbuf, hfin);

    proj_kernel<<<(B_ * C_ + 255) / 256, 256, 0, stream>>>(hfin, Wph, bp, (float*)d_out);
}